// Round 1
// baseline (606.046 us; speedup 1.0000x reference)
//
#include <hip/hip_runtime.h>

#define N_NODES 100000
#define N_EDGES 1600000

constexpr float NEG_SLOPE = 0.2f;

__device__ __forceinline__ float leaky(float x) { return x > 0.f ? x : NEG_SLOPE * x; }

// ---------------- CSR build (by dst) ----------------
__global__ void count_kernel(const int* __restrict__ dst, int* __restrict__ counts, int E) {
    int i = blockIdx.x * blockDim.x + threadIdx.x;
    if (i < E) atomicAdd(&counts[dst[i]], 1);
}

__global__ void scan1_kernel(const int* __restrict__ counts, int* __restrict__ row_ptr,
                             int* __restrict__ partials, int N) {
    __shared__ int sh[1024];
    int tid = threadIdx.x;
    int i = blockIdx.x * 1024 + tid;
    int v = (i < N) ? counts[i] : 0;
    sh[tid] = v;
    __syncthreads();
    for (int off = 1; off < 1024; off <<= 1) {
        int t = (tid >= off) ? sh[tid - off] : 0;
        __syncthreads();
        sh[tid] += t;
        __syncthreads();
    }
    if (i < N) row_ptr[i] = sh[tid] - v;  // exclusive prefix within block
    if (tid == 1023) partials[blockIdx.x] = sh[tid];
}

__global__ void scan2_kernel(int* partials, int nb) {
    if (threadIdx.x == 0 && blockIdx.x == 0) {
        int run = 0;
        for (int i = 0; i < nb; ++i) { int v = partials[i]; partials[i] = run; run += v; }
    }
}

__global__ void scan3_kernel(int* __restrict__ row_ptr, const int* __restrict__ partials,
                             int N, int E) {
    int i = blockIdx.x * 1024 + threadIdx.x;
    if (i < N) row_ptr[i] += partials[blockIdx.x];
    if (i == 0) row_ptr[N] = E;
}

__global__ void scatter_kernel(const int* __restrict__ src, const int* __restrict__ dst,
                               const int* __restrict__ row_ptr, int* __restrict__ cursor,
                               int* __restrict__ csr_src, int E) {
    int i = blockIdx.x * blockDim.x + threadIdx.x;
    if (i < E) {
        int d = dst[i];
        int pos = row_ptr[d] + atomicAdd(&cursor[d], 1);
        csr_src[pos] = src[i];
    }
}

// ---------------- Fused GEMM (row per thread) + el/er epilogue ----------------
template <int DIN, int DOUT>
__global__ void gemm_row_kernel(const float* __restrict__ X, const float* __restrict__ W,
                                const float* __restrict__ al, const float* __restrict__ ar,
                                float* __restrict__ outf, float* __restrict__ el,
                                float* __restrict__ er, int N) {
    int r = blockIdx.x * blockDim.x + threadIdx.x;
    if (r >= N) return;
    float acc[DOUT];
#pragma unroll
    for (int c = 0; c < DOUT; ++c) acc[c] = 0.f;
    const float4* X4 = reinterpret_cast<const float4*>(X + (size_t)r * DIN);
    for (int k4 = 0; k4 < DIN / 4; ++k4) {
        float4 xv4 = X4[k4];
        float xv[4] = {xv4.x, xv4.y, xv4.z, xv4.w};
#pragma unroll
        for (int kk = 0; kk < 4; ++kk) {
            const float4* wr = reinterpret_cast<const float4*>(W + (k4 * 4 + kk) * DOUT);
#pragma unroll
            for (int c4 = 0; c4 < DOUT / 4; ++c4) {
                float4 w = wr[c4];
                acc[c4 * 4 + 0] += xv[kk] * w.x;
                acc[c4 * 4 + 1] += xv[kk] * w.y;
                acc[c4 * 4 + 2] += xv[kk] * w.z;
                acc[c4 * 4 + 3] += xv[kk] * w.w;
            }
        }
    }
    float elv = 0.f, erv = 0.f;
#pragma unroll
    for (int c = 0; c < DOUT; ++c) { elv += acc[c] * al[c]; erv += acc[c] * ar[c]; }
    el[r] = elv;
    er[r] = erv;
    float4* O4 = reinterpret_cast<float4*>(outf + (size_t)r * DOUT);
#pragma unroll
    for (int c4 = 0; c4 < DOUT / 4; ++c4)
        O4[c4] = make_float4(acc[c4 * 4 + 0], acc[c4 * 4 + 1], acc[c4 * 4 + 2], acc[c4 * 4 + 3]);
}

// ---------------- Segment softmax + weighted aggregation: one wave per dst node ----------------
template <int DOUT, bool ELU>
__global__ void agg_kernel(const int* __restrict__ row_ptr, const int* __restrict__ csr_src,
                           const float* __restrict__ el, const float* __restrict__ er,
                           const float* __restrict__ feat, const float* __restrict__ bias,
                           float* __restrict__ outp, int N) {
    int lane = threadIdx.x & 63;
    int wid = threadIdx.x >> 6;
    int n = blockIdx.x * (blockDim.x >> 6) + wid;
    if (n >= N) return;
    int beg = row_ptr[n];
    int end = row_ptr[n + 1];
    float ern = er[n];

    // pass 1: segment max
    float m = -1e30f;
    for (int j = beg + lane; j < end; j += 64) {
        float e = leaky(el[csr_src[j]] + ern);
        m = fmaxf(m, e);
    }
#pragma unroll
    for (int o = 32; o > 0; o >>= 1) m = fmaxf(m, __shfl_xor(m, o, 64));

    // pass 2: unnormalized weighted accumulation + denominator
    float ssum = 0.f;
    float acc = 0.f;
    for (int base = beg; base < end; base += 64) {
        int j = base + lane;
        int cnt = min(64, end - base);
        int s = (lane < cnt) ? csr_src[j] : 0;
        float ee = 0.f;
        if (lane < cnt) {
            float e = leaky(el[s] + ern);
            ee = __expf(e - m);
        }
        ssum += ee;
        for (int t = 0; t < cnt; ++t) {
            float w = __shfl(ee, t, 64);
            int sj = __shfl(s, t, 64);
            if (lane < DOUT) acc += w * feat[(size_t)sj * DOUT + lane];
        }
    }
#pragma unroll
    for (int o = 32; o > 0; o >>= 1) ssum += __shfl_xor(ssum, o, 64);

    if (lane < DOUT) {
        float o = (end > beg) ? acc / ssum : 0.f;
        o += bias[lane];
        if (ELU) o = (o > 0.f) ? o : (__expf(o) - 1.f);
        outp[(size_t)n * DOUT + lane] = o;
    }
}

extern "C" void kernel_launch(void* const* d_in, const int* in_sizes, int n_in,
                              void* d_out, int out_size, void* d_ws, size_t ws_size,
                              hipStream_t stream) {
    const float* in_feat = (const float*)d_in[0];
    const int* src = (const int*)d_in[1];
    const int* dst = (const int*)d_in[2];
    const float* W1 = (const float*)d_in[3];
    const float* al1 = (const float*)d_in[4];
    const float* ar1 = (const float*)d_in[5];
    const float* b1 = (const float*)d_in[6];
    const float* W2 = (const float*)d_in[7];
    const float* al2 = (const float*)d_in[8];
    const float* ar2 = (const float*)d_in[9];
    const float* b2 = (const float*)d_in[10];
    float* out = (float*)d_out;

    const int N = N_NODES, E = N_EDGES;

    // workspace carve (aligned to 256B)
    size_t off = 0;
    auto carve = [&](size_t bytes) {
        void* p = (char*)d_ws + off;
        off += (bytes + 255) & ~(size_t)255;
        return p;
    };
    float* feat1 = (float*)carve((size_t)N * 64 * 4);  // layer1 feat; reused as feat2 (N*40)
    float* h     = (float*)carve((size_t)N * 64 * 4);  // elu(agg1)
    float* el    = (float*)carve((size_t)N * 4);       // reused per layer
    float* er    = (float*)carve((size_t)N * 4);
    int* row_ptr = (int*)carve((size_t)(N + 1) * 4);
    int* counts  = (int*)carve((size_t)N * 4);
    int* cursor  = (int*)carve((size_t)N * 4);
    int* csr_src = (int*)carve((size_t)E * 4);
    int* partials = (int*)carve(1024 * 4);
    float* feat2 = feat1;  // alias: feat1 dead after agg1

    hipMemsetAsync(counts, 0, (size_t)N * 4, stream);
    hipMemsetAsync(cursor, 0, (size_t)N * 4, stream);

    // CSR build (shared by both layers)
    int egrid = (E + 255) / 256;
    count_kernel<<<egrid, 256, 0, stream>>>(dst, counts, E);
    int nb = (N + 1023) / 1024;  // 98
    scan1_kernel<<<nb, 1024, 0, stream>>>(counts, row_ptr, partials, N);
    scan2_kernel<<<1, 64, 0, stream>>>(partials, nb);
    scan3_kernel<<<nb, 1024, 0, stream>>>(row_ptr, partials, N, E);
    scatter_kernel<<<egrid, 256, 0, stream>>>(src, dst, row_ptr, cursor, csr_src, E);

    int ngrid = (N + 255) / 256;
    int agrid = (N + 3) / 4;  // 4 waves per 256-thread block

    // layer 1
    gemm_row_kernel<128, 64><<<ngrid, 256, 0, stream>>>(in_feat, W1, al1, ar1, feat1, el, er, N);
    agg_kernel<64, true><<<agrid, 256, 0, stream>>>(row_ptr, csr_src, el, er, feat1, b1, h, N);

    // layer 2
    gemm_row_kernel<64, 40><<<ngrid, 256, 0, stream>>>(h, W2, al2, ar2, feat2, el, er, N);
    agg_kernel<40, false><<<agrid, 256, 0, stream>>>(row_ptr, csr_src, el, er, feat2, b2, out, N);
}

// Round 2
// 497.832 us; speedup vs baseline: 1.2174x; 1.2174x over previous
//
#include <hip/hip_runtime.h>

#define N_NODES 100000
#define N_EDGES 1600000

constexpr float NEG_SLOPE = 0.2f;

__device__ __forceinline__ float leaky(float x) { return x > 0.f ? x : NEG_SLOPE * x; }

// ---------------- CSR build (by dst) ----------------
__global__ void count_kernel(const int* __restrict__ dst, int* __restrict__ counts, int E) {
    int i = blockIdx.x * blockDim.x + threadIdx.x;
    if (i < E) atomicAdd(&counts[dst[i]], 1);
}

__global__ void scan1_kernel(const int* __restrict__ counts, int* __restrict__ row_ptr,
                             int* __restrict__ partials, int N) {
    __shared__ int sh[1024];
    int tid = threadIdx.x;
    int i = blockIdx.x * 1024 + tid;
    int v = (i < N) ? counts[i] : 0;
    sh[tid] = v;
    __syncthreads();
    for (int off = 1; off < 1024; off <<= 1) {
        int t = (tid >= off) ? sh[tid - off] : 0;
        __syncthreads();
        sh[tid] += t;
        __syncthreads();
    }
    if (i < N) row_ptr[i] = sh[tid] - v;  // exclusive prefix within block
    if (tid == 1023) partials[blockIdx.x] = sh[tid];
}

__global__ void scan2_kernel(int* partials, int nb) {
    if (threadIdx.x == 0 && blockIdx.x == 0) {
        int run = 0;
        for (int i = 0; i < nb; ++i) { int v = partials[i]; partials[i] = run; run += v; }
    }
}

__global__ void scan3_kernel(int* __restrict__ row_ptr, const int* __restrict__ partials,
                             int N, int E) {
    int i = blockIdx.x * 1024 + threadIdx.x;
    if (i < N) row_ptr[i] += partials[blockIdx.x];
    if (i == 0) row_ptr[N] = E;
}

__global__ void scatter_kernel(const int* __restrict__ src, const int* __restrict__ dst,
                               const int* __restrict__ row_ptr, int* __restrict__ cursor,
                               int* __restrict__ csr_src, int E) {
    int i = blockIdx.x * blockDim.x + threadIdx.x;
    if (i < E) {
        int d = dst[i];
        int pos = row_ptr[d] + atomicAdd(&cursor[d], 1);
        csr_src[pos] = src[i];
    }
}

// ---------------- Fused GEMM (row per thread) + el/er epilogue ----------------
template <int DIN, int DOUT, int OSTR>
__global__ void gemm_row_kernel(const float* __restrict__ X, const float* __restrict__ W,
                                const float* __restrict__ al, const float* __restrict__ ar,
                                float* __restrict__ outf, float* __restrict__ el,
                                float* __restrict__ er, int N) {
    int r = blockIdx.x * blockDim.x + threadIdx.x;
    if (r >= N) return;
    float acc[DOUT];
#pragma unroll
    for (int c = 0; c < DOUT; ++c) acc[c] = 0.f;
    const float4* X4 = reinterpret_cast<const float4*>(X + (size_t)r * DIN);
    for (int k4 = 0; k4 < DIN / 4; ++k4) {
        float4 xv4 = X4[k4];
        float xv[4] = {xv4.x, xv4.y, xv4.z, xv4.w};
#pragma unroll
        for (int kk = 0; kk < 4; ++kk) {
            const float4* wr = reinterpret_cast<const float4*>(W + (k4 * 4 + kk) * DOUT);
#pragma unroll
            for (int c4 = 0; c4 < DOUT / 4; ++c4) {
                float4 w = wr[c4];
                acc[c4 * 4 + 0] += xv[kk] * w.x;
                acc[c4 * 4 + 1] += xv[kk] * w.y;
                acc[c4 * 4 + 2] += xv[kk] * w.z;
                acc[c4 * 4 + 3] += xv[kk] * w.w;
            }
        }
    }
    float elv = 0.f, erv = 0.f;
#pragma unroll
    for (int c = 0; c < DOUT; ++c) { elv += acc[c] * al[c]; erv += acc[c] * ar[c]; }
    el[r] = elv;
    er[r] = erv;
    float4* O4 = reinterpret_cast<float4*>(outf + (size_t)r * OSTR);
#pragma unroll
    for (int c4 = 0; c4 < DOUT / 4; ++c4)
        O4[c4] = make_float4(acc[c4 * 4 + 0], acc[c4 * 4 + 1], acc[c4 * 4 + 2], acc[c4 * 4 + 3]);
}

// ---------------- Segment softmax + aggregation ----------------
// One wave per dst node. Fast path (deg<=64): edge scores cached in registers,
// then 4 edges processed per iteration (4 groups x 16 lanes, float4 row loads).
template <int DOUT, int FSTR, int OSTR, bool ELU>
__global__ void agg_kernel(const int* __restrict__ row_ptr, const int* __restrict__ csr_src,
                           const float* __restrict__ el, const float* __restrict__ er,
                           const float* __restrict__ feat, const float* __restrict__ bias,
                           float* __restrict__ outp, int N) {
    int lane = threadIdx.x & 63;
    int n = blockIdx.x * (blockDim.x >> 6) + (threadIdx.x >> 6);
    if (n >= N) return;
    int beg = row_ptr[n];
    int end = row_ptr[n + 1];
    int deg = end - beg;
    float ern = er[n];

    constexpr int G4 = (DOUT + 3) / 4;  // float4s per row (16 for 64, 10 for 40)

    if (deg <= 64) {
        // ---- pass 1 in registers ----
        int s = 0;
        float e = -1e30f;
        bool act = lane < deg;
        if (act) {
            s = csr_src[beg + lane];
            e = leaky(el[s] + ern);
        }
        float m = e;
#pragma unroll
        for (int o = 32; o > 0; o >>= 1) m = fmaxf(m, __shfl_xor(m, o, 64));
        float ee = act ? __expf(e - m) : 0.f;
        float ssum = ee;
#pragma unroll
        for (int o = 32; o > 0; o >>= 1) ssum += __shfl_xor(ssum, o, 64);

        // ---- 4-edge-parallel gather ----
        int g = lane >> 4;    // group 0..3 -> edge slot
        int cl = lane & 15;   // float4 index within row
        float4 acc = make_float4(0.f, 0.f, 0.f, 0.f);
        int niter = (deg + 3) >> 2;
        for (int i = 0; i < niter; i += 2) {
            int e0 = 4 * i + g;
            int e1 = e0 + 4;
            float w0 = __shfl(ee, e0 & 63, 64);
            int s0 = __shfl(s, e0 & 63, 64);
            float w1 = __shfl(ee, e1 & 63, 64);
            int s1 = __shfl(s, e1 & 63, 64);
            if (e0 >= deg) w0 = 0.f;
            if (e1 >= deg) w1 = 0.f;
            if (cl < G4) {
                const float4* r0 = reinterpret_cast<const float4*>(feat + (size_t)s0 * FSTR);
                const float4* r1 = reinterpret_cast<const float4*>(feat + (size_t)s1 * FSTR);
                float4 f0 = r0[cl];
                float4 f1 = r1[cl];
                acc.x += w0 * f0.x + w1 * f1.x;
                acc.y += w0 * f0.y + w1 * f1.y;
                acc.z += w0 * f0.z + w1 * f1.z;
                acc.w += w0 * f0.w + w1 * f1.w;
            }
        }
        // reduce across the 4 groups (lanes cl, cl+16, cl+32, cl+48)
#pragma unroll
        for (int o = 16; o <= 32; o <<= 1) {
            acc.x += __shfl_xor(acc.x, o, 64);
            acc.y += __shfl_xor(acc.y, o, 64);
            acc.z += __shfl_xor(acc.z, o, 64);
            acc.w += __shfl_xor(acc.w, o, 64);
        }
        if (g == 0 && cl < G4) {
            float inv = (deg > 0) ? 1.f / ssum : 0.f;
            const float4 b4 = reinterpret_cast<const float4*>(bias)[cl];
            float4 o4;
            o4.x = acc.x * inv + b4.x;
            o4.y = acc.y * inv + b4.y;
            o4.z = acc.z * inv + b4.z;
            o4.w = acc.w * inv + b4.w;
            if (ELU) {
                o4.x = o4.x > 0.f ? o4.x : (__expf(o4.x) - 1.f);
                o4.y = o4.y > 0.f ? o4.y : (__expf(o4.y) - 1.f);
                o4.z = o4.z > 0.f ? o4.z : (__expf(o4.z) - 1.f);
                o4.w = o4.w > 0.f ? o4.w : (__expf(o4.w) - 1.f);
            }
            *reinterpret_cast<float4*>(outp + (size_t)n * OSTR + 4 * cl) = o4;
        }
        return;
    }

    // ---- slow path (deg > 64): streaming two-pass (rare) ----
    float m = -1e30f;
    for (int j = beg + lane; j < end; j += 64) {
        float e = leaky(el[csr_src[j]] + ern);
        m = fmaxf(m, e);
    }
#pragma unroll
    for (int o = 32; o > 0; o >>= 1) m = fmaxf(m, __shfl_xor(m, o, 64));

    float ssum = 0.f;
    float acc = 0.f;
    for (int base = beg; base < end; base += 64) {
        int j = base + lane;
        int cnt = min(64, end - base);
        int s = (lane < cnt) ? csr_src[j] : 0;
        float ee = 0.f;
        if (lane < cnt) {
            float e = leaky(el[s] + ern);
            ee = __expf(e - m);
        }
        ssum += ee;
        for (int t = 0; t < cnt; ++t) {
            float w = __shfl(ee, t, 64);
            int sj = __shfl(s, t, 64);
            if (lane < DOUT) acc += w * feat[(size_t)sj * FSTR + lane];
        }
    }
#pragma unroll
    for (int o = 32; o > 0; o >>= 1) ssum += __shfl_xor(ssum, o, 64);

    if (lane < DOUT) {
        float o = acc / ssum + bias[lane];
        if (ELU) o = (o > 0.f) ? o : (__expf(o) - 1.f);
        outp[(size_t)n * OSTR + lane] = o;
    }
}

extern "C" void kernel_launch(void* const* d_in, const int* in_sizes, int n_in,
                              void* d_out, int out_size, void* d_ws, size_t ws_size,
                              hipStream_t stream) {
    const float* in_feat = (const float*)d_in[0];
    const int* src = (const int*)d_in[1];
    const int* dst = (const int*)d_in[2];
    const float* W1 = (const float*)d_in[3];
    const float* al1 = (const float*)d_in[4];
    const float* ar1 = (const float*)d_in[5];
    const float* b1 = (const float*)d_in[6];
    const float* W2 = (const float*)d_in[7];
    const float* al2 = (const float*)d_in[8];
    const float* ar2 = (const float*)d_in[9];
    const float* b2 = (const float*)d_in[10];
    float* out = (float*)d_out;

    const int N = N_NODES, E = N_EDGES;

    size_t off = 0;
    auto carve = [&](size_t bytes) {
        void* p = (char*)d_ws + off;
        off += (bytes + 255) & ~(size_t)255;
        return p;
    };
    float* feat1 = (float*)carve((size_t)N * 64 * 4);  // layer1 feat; reused as feat2 (N*48 padded)
    float* h     = (float*)carve((size_t)N * 64 * 4);  // elu(agg1)
    float* el    = (float*)carve((size_t)N * 4);
    float* er    = (float*)carve((size_t)N * 4);
    int* row_ptr = (int*)carve((size_t)(N + 1) * 4);
    int* counts  = (int*)carve((size_t)N * 4);
    int* cursor  = (int*)carve((size_t)N * 4);
    int* csr_src = (int*)carve((size_t)E * 4);
    int* partials = (int*)carve(1024 * 4);
    float* feat2 = feat1;  // alias: feat1 dead after agg1; stride 48

    hipMemsetAsync(counts, 0, (size_t)N * 4, stream);
    hipMemsetAsync(cursor, 0, (size_t)N * 4, stream);

    int egrid = (E + 255) / 256;
    count_kernel<<<egrid, 256, 0, stream>>>(dst, counts, E);
    int nb = (N + 1023) / 1024;
    scan1_kernel<<<nb, 1024, 0, stream>>>(counts, row_ptr, partials, N);
    scan2_kernel<<<1, 64, 0, stream>>>(partials, nb);
    scan3_kernel<<<nb, 1024, 0, stream>>>(row_ptr, partials, N, E);
    scatter_kernel<<<egrid, 256, 0, stream>>>(src, dst, row_ptr, cursor, csr_src, E);

    int ngrid = (N + 255) / 256;
    int agrid = (N + 3) / 4;  // 4 waves per 256-thread block

    // layer 1
    gemm_row_kernel<128, 64, 64><<<ngrid, 256, 0, stream>>>(in_feat, W1, al1, ar1, feat1, el, er, N);
    agg_kernel<64, 64, 64, true><<<agrid, 256, 0, stream>>>(row_ptr, csr_src, el, er, feat1, b1, h, N);

    // layer 2 (feat2 row stride 48 so float4 loads stay aligned for DOUT=40)
    gemm_row_kernel<64, 40, 48><<<ngrid, 256, 0, stream>>>(h, W2, al2, ar2, feat2, el, er, N);
    agg_kernel<40, 48, 40, false><<<agrid, 256, 0, stream>>>(row_ptr, csr_src, el, er, feat2, b2, out, N);
}

// Round 3
// 424.291 us; speedup vs baseline: 1.4284x; 1.1733x over previous
//
#include <hip/hip_runtime.h>

#define N_NODES 100000
#define N_EDGES 1600000
#define BKT_SHIFT 13
#define BKT_SIZE 8192
#define NB 196  // ceil(N_EDGES / BKT_SIZE)

constexpr float NEG_SLOPE = 0.2f;

__device__ __forceinline__ float leaky(float x) { return x > 0.f ? x : NEG_SLOPE * x; }

// ---------------- CSR build (counting sort by dst, no random global writes) ----------------
__global__ void count_rank_kernel(const int* __restrict__ dst, int* __restrict__ counts,
                                  unsigned short* __restrict__ rank, int E) {
    int i = blockIdx.x * blockDim.x + threadIdx.x;
    if (i < E) rank[i] = (unsigned short)atomicAdd(&counts[dst[i]], 1);
}

__global__ void scan1_kernel(const int* __restrict__ counts, int* __restrict__ row_ptr,
                             int* __restrict__ partials, int N) {
    __shared__ int sh[1024];
    int tid = threadIdx.x;
    int i = blockIdx.x * 1024 + tid;
    int v = (i < N) ? counts[i] : 0;
    sh[tid] = v;
    __syncthreads();
    for (int off = 1; off < 1024; off <<= 1) {
        int t = (tid >= off) ? sh[tid - off] : 0;
        __syncthreads();
        sh[tid] += t;
        __syncthreads();
    }
    if (i < N) row_ptr[i] = sh[tid] - v;  // exclusive prefix within block
    if (tid == 1023) partials[blockIdx.x] = sh[tid];
}

__global__ void scan2_kernel(int* partials, int nb) {
    if (threadIdx.x == 0 && blockIdx.x == 0) {
        int run = 0;
        for (int i = 0; i < nb; ++i) { int v = partials[i]; partials[i] = run; run += v; }
    }
}

__global__ void scan3_kernel(int* __restrict__ row_ptr, const int* __restrict__ partials,
                             int N, int E) {
    int i = blockIdx.x * 1024 + threadIdx.x;
    if (i < N) row_ptr[i] += partials[blockIdx.x];
    if (i == 0) row_ptr[N] = E;
}

// Partition edges into position-buckets (pos>>13). Per block: 4096 edges staged and
// ordered in LDS, then written as coalesced per-bucket runs. Payload = (pos_local<<17)|src.
__global__ __launch_bounds__(256) void partition_kernel(
        const int* __restrict__ src, const int* __restrict__ dst,
        const unsigned short* __restrict__ rank, const int* __restrict__ row_ptr,
        int* __restrict__ bucket_cursor, unsigned* __restrict__ staged, int E) {
    __shared__ unsigned pos_s[4096];
    __shared__ unsigned stage[4096];
    __shared__ unsigned char bkt_s[4096];
    __shared__ unsigned hist[256];
    __shared__ unsigned scanb[256];
    __shared__ unsigned baseg[256];
    __shared__ unsigned cnt[256];
    int tid = threadIdx.x;
    int e0 = blockIdx.x * 4096;
    hist[tid] = 0;
    cnt[tid] = 0;
    __syncthreads();
#pragma unroll
    for (int k = 0; k < 16; ++k) {
        int idx = k * 256 + tid;
        int i = e0 + idx;
        unsigned p = 0u;
        if (i < E) {
            int d = dst[i];
            p = (unsigned)(row_ptr[d] + (int)rank[i]);
            atomicAdd(&hist[p >> BKT_SHIFT], 1u);
        }
        pos_s[idx] = p;
    }
    __syncthreads();
    unsigned v = hist[tid];
    scanb[tid] = v;
    __syncthreads();
    for (int off = 1; off < 256; off <<= 1) {
        unsigned t = (tid >= off) ? scanb[tid - off] : 0;
        __syncthreads();
        scanb[tid] += t;
        __syncthreads();
    }
    unsigned excl = scanb[tid] - v;
    __syncthreads();
    scanb[tid] = excl;
    if (tid < NB)
        baseg[tid] = (unsigned)(tid * BKT_SIZE) + (unsigned)atomicAdd(&bucket_cursor[tid], (int)v);
    __syncthreads();
#pragma unroll
    for (int k = 0; k < 16; ++k) {
        int idx = k * 256 + tid;
        int i = e0 + idx;
        if (i < E) {
            unsigned p = pos_s[idx];
            unsigned b = p >> BKT_SHIFT;
            unsigned slot = scanb[b] + atomicAdd(&cnt[b], 1u);
            stage[slot] = ((p & (BKT_SIZE - 1)) << 17) | (unsigned)src[i];
            bkt_s[slot] = (unsigned char)b;
        }
    }
    __syncthreads();
    int total = min(4096, E - e0);
    for (int j = tid; j < total; j += 256) {
        unsigned b = bkt_s[j];
        unsigned addr = baseg[b] + ((unsigned)j - scanb[b]);
        staged[addr] = stage[j];
    }
}

// One block per bucket: coalesced read of staged payloads, scatter inside LDS,
// coalesced flush to csr_src.
__global__ __launch_bounds__(256) void bucket_kernel(const unsigned* __restrict__ staged,
                                                     int* __restrict__ csr_src, int E) {
    __shared__ int lsrc[BKT_SIZE];
    int base = blockIdx.x * BKT_SIZE;
    int count = min(BKT_SIZE, E - base);
    for (int j = threadIdx.x; j < count; j += 256) {
        unsigned pl = staged[base + j];
        lsrc[pl >> 17] = (int)(pl & 0x1FFFFu);
    }
    __syncthreads();
    const int4* ls4 = reinterpret_cast<const int4*>(lsrc);
    int4* out4 = reinterpret_cast<int4*>(csr_src + base);
    int c4 = count >> 2;
    for (int j = threadIdx.x; j < c4; j += 256) out4[j] = ls4[j];
    for (int j = (c4 << 2) + threadIdx.x; j < count; j += 256) csr_src[base + j] = lsrc[j];
}

// ---------------- Fused GEMM (row per thread) + el/er epilogue ----------------
template <int DIN, int DOUT, int OSTR>
__global__ void gemm_row_kernel(const float* __restrict__ X, const float* __restrict__ W,
                                const float* __restrict__ al, const float* __restrict__ ar,
                                float* __restrict__ outf, float* __restrict__ el,
                                float* __restrict__ er, int N) {
    int r = blockIdx.x * blockDim.x + threadIdx.x;
    if (r >= N) return;
    float acc[DOUT];
#pragma unroll
    for (int c = 0; c < DOUT; ++c) acc[c] = 0.f;
    const float4* X4 = reinterpret_cast<const float4*>(X + (size_t)r * DIN);
    for (int k4 = 0; k4 < DIN / 4; ++k4) {
        float4 xv4 = X4[k4];
        float xv[4] = {xv4.x, xv4.y, xv4.z, xv4.w};
#pragma unroll
        for (int kk = 0; kk < 4; ++kk) {
            const float4* wr = reinterpret_cast<const float4*>(W + (k4 * 4 + kk) * DOUT);
#pragma unroll
            for (int c4 = 0; c4 < DOUT / 4; ++c4) {
                float4 w = wr[c4];
                acc[c4 * 4 + 0] += xv[kk] * w.x;
                acc[c4 * 4 + 1] += xv[kk] * w.y;
                acc[c4 * 4 + 2] += xv[kk] * w.z;
                acc[c4 * 4 + 3] += xv[kk] * w.w;
            }
        }
    }
    float elv = 0.f, erv = 0.f;
#pragma unroll
    for (int c = 0; c < DOUT; ++c) { elv += acc[c] * al[c]; erv += acc[c] * ar[c]; }
    el[r] = elv;
    er[r] = erv;
    float4* O4 = reinterpret_cast<float4*>(outf + (size_t)r * OSTR);
#pragma unroll
    for (int c4 = 0; c4 < DOUT / 4; ++c4)
        O4[c4] = make_float4(acc[c4 * 4 + 0], acc[c4 * 4 + 1], acc[c4 * 4 + 2], acc[c4 * 4 + 3]);
}

// ---------------- Segment softmax + aggregation ----------------
template <int DOUT, int FSTR, int OSTR, bool ELU>
__global__ void agg_kernel(const int* __restrict__ row_ptr, const int* __restrict__ csr_src,
                           const float* __restrict__ el, const float* __restrict__ er,
                           const float* __restrict__ feat, const float* __restrict__ bias,
                           float* __restrict__ outp, int N) {
    int lane = threadIdx.x & 63;
    int n = blockIdx.x * (blockDim.x >> 6) + (threadIdx.x >> 6);
    if (n >= N) return;
    int beg = row_ptr[n];
    int end = row_ptr[n + 1];
    int deg = end - beg;
    float ern = er[n];

    constexpr int G4 = (DOUT + 3) / 4;

    if (deg <= 64) {
        int s = 0;
        float e = -1e30f;
        bool act = lane < deg;
        if (act) {
            s = csr_src[beg + lane];
            e = leaky(el[s] + ern);
        }
        float m = e;
#pragma unroll
        for (int o = 32; o > 0; o >>= 1) m = fmaxf(m, __shfl_xor(m, o, 64));
        float ee = act ? __expf(e - m) : 0.f;
        float ssum = ee;
#pragma unroll
        for (int o = 32; o > 0; o >>= 1) ssum += __shfl_xor(ssum, o, 64);

        int g = lane >> 4;
        int cl = lane & 15;
        float4 acc = make_float4(0.f, 0.f, 0.f, 0.f);
        int niter = (deg + 3) >> 2;
        for (int i = 0; i < niter; i += 2) {
            int e0 = 4 * i + g;
            int e1 = e0 + 4;
            float w0 = __shfl(ee, e0 & 63, 64);
            int s0 = __shfl(s, e0 & 63, 64);
            float w1 = __shfl(ee, e1 & 63, 64);
            int s1 = __shfl(s, e1 & 63, 64);
            if (e0 >= deg) w0 = 0.f;
            if (e1 >= deg) w1 = 0.f;
            if (cl < G4) {
                const float4* r0 = reinterpret_cast<const float4*>(feat + (size_t)s0 * FSTR);
                const float4* r1 = reinterpret_cast<const float4*>(feat + (size_t)s1 * FSTR);
                float4 f0 = r0[cl];
                float4 f1 = r1[cl];
                acc.x += w0 * f0.x + w1 * f1.x;
                acc.y += w0 * f0.y + w1 * f1.y;
                acc.z += w0 * f0.z + w1 * f1.z;
                acc.w += w0 * f0.w + w1 * f1.w;
            }
        }
#pragma unroll
        for (int o = 16; o <= 32; o <<= 1) {
            acc.x += __shfl_xor(acc.x, o, 64);
            acc.y += __shfl_xor(acc.y, o, 64);
            acc.z += __shfl_xor(acc.z, o, 64);
            acc.w += __shfl_xor(acc.w, o, 64);
        }
        if (g == 0 && cl < G4) {
            float inv = (deg > 0) ? 1.f / ssum : 0.f;
            const float4 b4 = reinterpret_cast<const float4*>(bias)[cl];
            float4 o4;
            o4.x = acc.x * inv + b4.x;
            o4.y = acc.y * inv + b4.y;
            o4.z = acc.z * inv + b4.z;
            o4.w = acc.w * inv + b4.w;
            if (ELU) {
                o4.x = o4.x > 0.f ? o4.x : (__expf(o4.x) - 1.f);
                o4.y = o4.y > 0.f ? o4.y : (__expf(o4.y) - 1.f);
                o4.z = o4.z > 0.f ? o4.z : (__expf(o4.z) - 1.f);
                o4.w = o4.w > 0.f ? o4.w : (__expf(o4.w) - 1.f);
            }
            *reinterpret_cast<float4*>(outp + (size_t)n * OSTR + 4 * cl) = o4;
        }
        return;
    }

    // slow path (deg > 64)
    float m = -1e30f;
    for (int j = beg + lane; j < end; j += 64) {
        float e = leaky(el[csr_src[j]] + ern);
        m = fmaxf(m, e);
    }
#pragma unroll
    for (int o = 32; o > 0; o >>= 1) m = fmaxf(m, __shfl_xor(m, o, 64));

    float ssum = 0.f;
    float acc = 0.f;
    for (int base = beg; base < end; base += 64) {
        int j = base + lane;
        int cnt = min(64, end - base);
        int s = (lane < cnt) ? csr_src[j] : 0;
        float ee = 0.f;
        if (lane < cnt) {
            float e = leaky(el[s] + ern);
            ee = __expf(e - m);
        }
        ssum += ee;
        for (int t = 0; t < cnt; ++t) {
            float w = __shfl(ee, t, 64);
            int sj = __shfl(s, t, 64);
            if (lane < DOUT) acc += w * feat[(size_t)sj * FSTR + lane];
        }
    }
#pragma unroll
    for (int o = 32; o > 0; o >>= 1) ssum += __shfl_xor(ssum, o, 64);

    if (lane < DOUT) {
        float o = acc / ssum + bias[lane];
        if (ELU) o = (o > 0.f) ? o : (__expf(o) - 1.f);
        outp[(size_t)n * OSTR + lane] = o;
    }
}

extern "C" void kernel_launch(void* const* d_in, const int* in_sizes, int n_in,
                              void* d_out, int out_size, void* d_ws, size_t ws_size,
                              hipStream_t stream) {
    const float* in_feat = (const float*)d_in[0];
    const int* src = (const int*)d_in[1];
    const int* dst = (const int*)d_in[2];
    const float* W1 = (const float*)d_in[3];
    const float* al1 = (const float*)d_in[4];
    const float* ar1 = (const float*)d_in[5];
    const float* b1 = (const float*)d_in[6];
    const float* W2 = (const float*)d_in[7];
    const float* al2 = (const float*)d_in[8];
    const float* ar2 = (const float*)d_in[9];
    const float* b2 = (const float*)d_in[10];
    float* out = (float*)d_out;

    const int N = N_NODES, E = N_EDGES;
    const int E_PAD = NB * BKT_SIZE;

    size_t off = 0;
    auto carve = [&](size_t bytes) {
        void* p = (char*)d_ws + off;
        off += (bytes + 255) & ~(size_t)255;
        return p;
    };
    // long-lived
    float* feat1 = (float*)carve((size_t)N * 64 * 4);   // reused as feat2 (stride 48)
    float* el    = (float*)carve((size_t)N * 4);
    float* er    = (float*)carve((size_t)N * 4);
    int* row_ptr = (int*)carve((size_t)(N + 1) * 4);
    int* csr_src = (int*)carve((size_t)E * 4);
    int* bucket_cursor = (int*)carve((size_t)NB * 4);
    // h overlaps the CSR-build temporaries (all dead before agg1 writes h)
    size_t offH = off;
    float* h = (float*)carve((size_t)N * 64 * 4);
    size_t off_end = off;
    off = offH;
    unsigned short* rank = (unsigned short*)carve((size_t)E * 2);
    unsigned* staged     = (unsigned*)carve((size_t)E_PAD * 4);
    int* counts          = (int*)carve((size_t)N * 4);
    int* partials        = (int*)carve(1024 * 4);
    off = off_end;
    float* feat2 = feat1;

    hipMemsetAsync(counts, 0, (size_t)N * 4, stream);
    hipMemsetAsync(bucket_cursor, 0, (size_t)NB * 4, stream);

    int egrid = (E + 255) / 256;
    count_rank_kernel<<<egrid, 256, 0, stream>>>(dst, counts, rank, E);
    int nb = (N + 1023) / 1024;
    scan1_kernel<<<nb, 1024, 0, stream>>>(counts, row_ptr, partials, N);
    scan2_kernel<<<1, 64, 0, stream>>>(partials, nb);
    scan3_kernel<<<nb, 1024, 0, stream>>>(row_ptr, partials, N, E);
    int pgrid = (E + 4095) / 4096;
    partition_kernel<<<pgrid, 256, 0, stream>>>(src, dst, rank, row_ptr, bucket_cursor, staged, E);
    bucket_kernel<<<NB, 256, 0, stream>>>(staged, csr_src, E);

    int ngrid = (N + 255) / 256;
    int agrid = (N + 3) / 4;

    // layer 1
    gemm_row_kernel<128, 64, 64><<<ngrid, 256, 0, stream>>>(in_feat, W1, al1, ar1, feat1, el, er, N);
    agg_kernel<64, 64, 64, true><<<agrid, 256, 0, stream>>>(row_ptr, csr_src, el, er, feat1, b1, h, N);

    // layer 2 (feat2 row stride 48 keeps float4 alignment for DOUT=40)
    gemm_row_kernel<64, 40, 48><<<ngrid, 256, 0, stream>>>(h, W2, al2, ar2, feat2, el, er, N);
    agg_kernel<40, 48, 40, false><<<agrid, 256, 0, stream>>>(row_ptr, csr_src, el, er, feat2, b2, out, N);
}